// Round 1
// 155.387 us; speedup vs baseline: 1.0482x; 1.0482x over previous
//
#include <hip/hip_runtime.h>
#include <hip/hip_bf16.h>
#include <hip/hip_fp16.h>
#include <stdint.h>

typedef _Float16 half8 __attribute__((ext_vector_type(8)));
typedef _Float16 half4_t __attribute__((ext_vector_type(4)));
typedef float f32x4 __attribute__((ext_vector_type(4)));

// async global->LDS, 16B per lane. LDS dst must be wave-uniform base + lane*16.
__device__ __forceinline__ void lds_load16(const _Float16* g, _Float16* l) {
    __builtin_amdgcn_global_load_lds(
        (const __attribute__((address_space(1))) void*)g,
        (__attribute__((address_space(3))) void*)l, 16, 0, 0);
}

// ---------------------------------------------------------------------------
// fp32 -> fp16 conversions: nodes (8192x512), Wcat = [Wq;Wk;Wv], Wo
// ---------------------------------------------------------------------------
__global__ __launch_bounds__(256) void prep_convert(
    const float* __restrict__ nodes, const float* __restrict__ wq,
    const float* __restrict__ wk, const float* __restrict__ wv,
    const float* __restrict__ wo,
    _Float16* __restrict__ x16, _Float16* __restrict__ wcat,
    _Float16* __restrict__ wo16)
{
    const int t = blockIdx.x * 256 + threadIdx.x;   // 0 .. 1048575
    {
        const float4 v = ((const float4*)nodes)[t];
        half4_t o;
        o[0] = (_Float16)v.x; o[1] = (_Float16)v.y;
        o[2] = (_Float16)v.z; o[3] = (_Float16)v.w;
        *(half4_t*)(x16 + (size_t)t * 4) = o;
    }
    if (t < 65536) {
        float4 v; half4_t o;
        v = ((const float4*)wq)[t];
        o[0]=(_Float16)v.x; o[1]=(_Float16)v.y; o[2]=(_Float16)v.z; o[3]=(_Float16)v.w;
        *(half4_t*)(wcat + (size_t)t * 4) = o;
        v = ((const float4*)wk)[t];
        o[0]=(_Float16)v.x; o[1]=(_Float16)v.y; o[2]=(_Float16)v.z; o[3]=(_Float16)v.w;
        *(half4_t*)(wcat + 262144 + (size_t)t * 4) = o;
        v = ((const float4*)wv)[t];
        o[0]=(_Float16)v.x; o[1]=(_Float16)v.y; o[2]=(_Float16)v.z; o[3]=(_Float16)v.w;
        *(half4_t*)(wcat + 524288 + (size_t)t * 4) = o;
        v = ((const float4*)wo)[t];
        o[0]=(_Float16)v.x; o[1]=(_Float16)v.y; o[2]=(_Float16)v.z; o[3]=(_Float16)v.w;
        *(half4_t*)(wo16 + (size_t)t * 4) = o;
    }
}

// ---------------------------------------------------------------------------
// QKV projection: X[8192,512] @ Wcat[1536,512]^T -> scatter q/k/v [bh][i][d]
// q is pre-scaled by (1/sqrt(64)) * log2(e) here, so attention can use
// exp2 directly (v_exp_f32 computes 2^x).
// ---------------------------------------------------------------------------
__global__ __launch_bounds__(256, 3) void gemm_qkv(
    const _Float16* __restrict__ X, const _Float16* __restrict__ Wcat,
    const float* __restrict__ bq, const float* __restrict__ bk,
    const float* __restrict__ bv,
    _Float16* __restrict__ q16, _Float16* __restrict__ k16,
    _Float16* __restrict__ v16)
{
    __shared__ _Float16 As[128 * 32];
    __shared__ _Float16 Bs[128 * 32];
    const int t = threadIdx.x;
    const int bm = blockIdx.x, bn = blockIdx.y;
    const int wave = t >> 6, lane = t & 63;
    const int wm = (wave >> 1) * 64, wn = (wave & 1) * 64;
    const int quad = lane >> 4, l16 = lane & 15;

    f32x4 acc[4][4];
#pragma unroll
    for (int a = 0; a < 4; a++)
#pragma unroll
        for (int b2 = 0; b2 < 4; b2++) acc[a][b2] = (f32x4){0.f, 0.f, 0.f, 0.f};

    const _Float16* Ab = X + (size_t)bm * 128 * 512;
    const _Float16* Bb = Wcat + (size_t)bn * 128 * 512;
    const int srow = t >> 2, scol = (t & 3) * 8;

    for (int k0 = 0; k0 < 512; k0 += 32) {
        __syncthreads();
        lds_load16(Ab + (size_t)srow * 512 + k0 + scol, As + t * 8);
        lds_load16(Ab + (size_t)(srow + 64) * 512 + k0 + scol, As + 2048 + t * 8);
        lds_load16(Bb + (size_t)srow * 512 + k0 + scol, Bs + t * 8);
        lds_load16(Bb + (size_t)(srow + 64) * 512 + k0 + scol, Bs + 2048 + t * 8);
        __syncthreads();
        half8 af[4], bf[4];
#pragma unroll
        for (int mi = 0; mi < 4; mi++)
            af[mi] = *(const half8*)&As[(wm + mi * 16 + l16) * 32 + quad * 8];
#pragma unroll
        for (int ni = 0; ni < 4; ni++)
            bf[ni] = *(const half8*)&Bs[(wn + ni * 16 + l16) * 32 + quad * 8];
#pragma unroll
        for (int mi = 0; mi < 4; mi++)
#pragma unroll
            for (int ni = 0; ni < 4; ni++)
                acc[mi][ni] = __builtin_amdgcn_mfma_f32_16x16x32_f16(
                    af[mi], bf[ni], acc[mi][ni], 0, 0, 0);
    }

    const int sel = bn >> 2;
    const float* bias = sel == 0 ? bq : (sel == 1 ? bk : bv);
    _Float16* outp = sel == 0 ? q16 : (sel == 1 ? k16 : v16);
    // q: fold 1/sqrt(D) * log2(e) so softmax runs in exp2 domain
    const float scale = sel == 0 ? 0.18033688011112042f : 1.0f;
    const int colbase = (bn & 3) * 128 + wn + l16;
#pragma unroll
    for (int mi = 0; mi < 4; mi++) {
#pragma unroll
        for (int r = 0; r < 4; r++) {
            const int m = bm * 128 + wm + mi * 16 + quad * 4 + r;
            const int ii = m >> 3, bb = m & 7;
#pragma unroll
            for (int ni = 0; ni < 4; ni++) {
                const int f = colbase + ni * 16;
                const int hh = f >> 6, dd = f & 63;
                const float val = (acc[mi][ni][r] + bias[f]) * scale;
                outp[(size_t)((bb * 8 + hh) * 1024 + ii) * 64 + dd] = (_Float16)val;
            }
        }
    }
}

// ---------------------------------------------------------------------------
// Flash-style MFMA attention v2.
//   - 512 threads (8 waves), QBLK=256 rows/block, grid (64,4) = 256 blocks
//     = 1 block/CU, 8 waves/CU; per-wave 32 q-rows (2 mt tiles).
//   - Q held in registers (A-frags), no Qs LDS array.
//   - exp2-domain softmax: q pre-scaled by log2e/8, rb *= log2e, the -8
//     shift folded into MFMA C-init -> per element just fma + v_exp + cvt.
//   - row-sum via ones-column MFMA (acc_l) -> no per-element adds, no
//     shuffle reduce; denominator uses the same f16-rounded P as numerator.
//   - V^T stored with XOR-swizzled row index: write conflicts 4-way -> ~2-way.
//   - LDS strides 72 (144 B) so every fragment access is an aligned b128.
//   - edge-bias regs double-buffered via 2x-unrolled jt loop (no copy).
// ---------------------------------------------------------------------------
__global__ __launch_bounds__(512, 2) void attn_fused(
    const _Float16* __restrict__ q16, const _Float16* __restrict__ k16,
    const _Float16* __restrict__ v16, const float* __restrict__ edges,
    const float* __restrict__ rel_bias, _Float16* __restrict__ attn16)
{
    __shared__ _Float16 Ks[64][72];      //  9,216 B
    __shared__ _Float16 Vts[64 * 72];    //  9,216 B  V^T, rows XOR-swizzled
    __shared__ _Float16 Ps[256][72];     // 36,864 B  total 55,296 B

    const int t = threadIdx.x;
    const int bh = blockIdx.x;
    const int b = bh >> 3, h = bh & 7;
    const int i0 = blockIdx.y << 8;
    const int wave = t >> 6, lane = t & 63;
    const int quad = lane >> 4, l16 = lane & 15;
    const float rb = rel_bias[h] * 1.4426950408889634f;   // log2(e)

    const _Float16* Qb = q16 + (size_t)bh * 65536;
    const _Float16* Kb = k16 + (size_t)bh * 65536;
    const _Float16* Vb = v16 + (size_t)bh * 65536;

    // ---- Q rows for this wave, in registers (A-frags), loaded once ----
    half8 aq[2][2];
#pragma unroll
    for (int mt = 0; mt < 2; mt++) {
        const _Float16* qp =
            Qb + (size_t)(i0 + wave * 32 + mt * 16 + l16) * 64 + quad * 8;
        aq[mt][0] = *(const half8*)(qp);
        aq[mt][1] = *(const half8*)(qp + 32);
    }

    f32x4 acc_o[2][4], acc_l[2];
#pragma unroll
    for (int mt = 0; mt < 2; mt++) {
        acc_l[mt] = (f32x4){0.f, 0.f, 0.f, 0.f};
#pragma unroll
        for (int nd = 0; nd < 4; nd++) acc_o[mt][nd] = (f32x4){0.f, 0.f, 0.f, 0.f};
    }

    const half8 ones8 = {(_Float16)1.f, (_Float16)1.f, (_Float16)1.f, (_Float16)1.f,
                         (_Float16)1.f, (_Float16)1.f, (_Float16)1.f, (_Float16)1.f};

    // staging map: each thread owns 8 elems of the 64x64 K and V tiles
    const int srow = t >> 3, scol = (t & 7) * 8;
    // V^T swizzle: element V[j][d] lives at Vts[d*72 + (j ^ swz(d))],
    // swz(d) = ((d&3)<<3) | (((d>>4)&3)<<4)  (bits >=3 only: b128-contiguous)
    const int vswb = srow ^ (((scol >> 4) & 3) << 4);
    const int jq8 = (quad ^ (l16 & 3)) * 8;   // (quad*8) ^ ((l16&3)<<3)

    // ---- pipeline prologue: loads for jt = 0 ----
    half8 kp, vp;
    float ebA[2][4][4], ebB[2][4][4];
    kp = *(const half8*)(Kb + (size_t)srow * 64 + scol);
    vp = *(const half8*)(Vb + (size_t)srow * 64 + scol);

#define EDGE_LOAD(DST, JB)                                                     \
    _Pragma("unroll")                                                          \
    for (int mt_ = 0; mt_ < 2; mt_++) {                                        \
        const size_t rowb_ =                                                   \
            (size_t)(i0 + wave * 32 + mt_ * 16 + quad * 4) * 1024 + (JB);      \
        _Pragma("unroll")                                                      \
        for (int nt_ = 0; nt_ < 4; nt_++)                                      \
            _Pragma("unroll")                                                  \
            for (int r_ = 0; r_ < 4; r_++)                                     \
                DST[mt_][nt_][r_] =                                            \
                    edges[rowb_ + (size_t)r_ * 1024 + nt_ * 16 + l16];         \
    }

    EDGE_LOAD(ebA, 0);

#define STEP(JT, CUR, NXT)                                                     \
    {                                                                          \
        __syncthreads();                                                       \
        *(half8*)&Ks[srow][scol] = kp;                                         \
        _Pragma("unroll")                                                      \
        for (int e_ = 0; e_ < 8; e_++)                                         \
            Vts[(scol + e_) * 72 + (vswb ^ ((e_ & 3) << 3))] = vp[e_];         \
        __syncthreads();                                                       \
        if ((JT) + 64 < 1024) {                                                \
            kp = *(const half8*)(Kb + (size_t)((JT) + 64 + srow) * 64 + scol); \
            vp = *(const half8*)(Vb + (size_t)((JT) + 64 + srow) * 64 + scol); \
            EDGE_LOAD(NXT, (JT) + 64);                                         \
        }                                                                      \
        f32x4 s_[2][4];                                                        \
        _Pragma("unroll")                                                      \
        for (int mt_ = 0; mt_ < 2; mt_++)                                      \
            _Pragma("unroll")                                                  \
            for (int nt_ = 0; nt_ < 4; nt_++)                                  \
                s_[mt_][nt_] = (f32x4){-8.f, -8.f, -8.f, -8.f};                \
        __builtin_amdgcn_s_setprio(1);                                         \
        _Pragma("unroll")                                                      \
        for (int kk_ = 0; kk_ < 2; kk_++) {                                    \
            half8 bk8_[4];                                                     \
            _Pragma("unroll")                                                  \
            for (int nt_ = 0; nt_ < 4; nt_++)                                  \
                bk8_[nt_] =                                                    \
                    *(const half8*)&Ks[nt_ * 16 + l16][kk_ * 32 + quad * 8];   \
            _Pragma("unroll")                                                  \
            for (int mt_ = 0; mt_ < 2; mt_++)                                  \
                _Pragma("unroll")                                              \
                for (int nt_ = 0; nt_ < 4; nt_++)                              \
                    s_[mt_][nt_] = __builtin_amdgcn_mfma_f32_16x16x32_f16(     \
                        aq[mt_][kk_], bk8_[nt_], s_[mt_][nt_], 0, 0, 0);       \
        }                                                                      \
        __builtin_amdgcn_s_setprio(0);                                         \
        _Pragma("unroll")                                                      \
        for (int mt_ = 0; mt_ < 2; mt_++)                                      \
            _Pragma("unroll")                                                  \
            for (int nt_ = 0; nt_ < 4; nt_++)                                  \
                _Pragma("unroll")                                              \
                for (int r_ = 0; r_ < 4; r_++) {                               \
                    const float p_ = __builtin_amdgcn_exp2f(                   \
                        fmaf(CUR[mt_][nt_][r_], rb, s_[mt_][nt_][r_]));        \
                    Ps[wave * 32 + mt_ * 16 + quad * 4 + r_][nt_ * 16 + l16] = \
                        (_Float16)p_;                                          \
                }                                                              \
        __builtin_amdgcn_s_setprio(1);                                         \
        _Pragma("unroll")                                                      \
        for (int kk_ = 0; kk_ < 2; kk_++) {                                    \
            half8 pa_[2];                                                      \
            _Pragma("unroll")                                                  \
            for (int mt_ = 0; mt_ < 2; mt_++)                                  \
                pa_[mt_] = *(const half8*)&Ps[wave * 32 + mt_ * 16 + l16]      \
                                             [kk_ * 32 + quad * 8];            \
            _Pragma("unroll")                                                  \
            for (int mt_ = 0; mt_ < 2; mt_++)                                  \
                acc_l[mt_] = __builtin_amdgcn_mfma_f32_16x16x32_f16(           \
                    pa_[mt_], ones8, acc_l[mt_], 0, 0, 0);                     \
            _Pragma("unroll")                                                  \
            for (int nd_ = 0; nd_ < 4; nd_++) {                                \
                const half8 vb8_ = *(const half8*)&Vts[                        \
                    (nd_ * 16 + l16) * 72 + ((kk_ * 32 + jq8) ^ (nd_ << 4))];  \
                _Pragma("unroll")                                              \
                for (int mt_ = 0; mt_ < 2; mt_++)                              \
                    acc_o[mt_][nd_] = __builtin_amdgcn_mfma_f32_16x16x32_f16(  \
                        pa_[mt_], vb8_, acc_o[mt_][nd_], 0, 0, 0);             \
            }                                                                  \
        }                                                                      \
        __builtin_amdgcn_s_setprio(0);                                         \
    }

    for (int jt = 0; jt < 1024; jt += 128) {
        STEP(jt, ebA, ebB);
        STEP(jt + 64, ebB, ebA);
    }
#undef STEP
#undef EDGE_LOAD

    // ---- finalize: acc_l holds row sums in the same C-layout as acc_o ----
#pragma unroll
    for (int mt = 0; mt < 2; mt++) {
#pragma unroll
        for (int r = 0; r < 4; r++) {
            const float inv = 1.0f / acc_l[mt][r];
            const int i = i0 + wave * 32 + mt * 16 + quad * 4 + r;
            _Float16* orow = attn16 + ((size_t)i * 8 + b) * 512 + h * 64;
#pragma unroll
            for (int nd = 0; nd < 4; nd++)
                orow[nd * 16 + l16] = (_Float16)(acc_o[mt][nd][r] * inv);
        }
    }
}

// ---------------------------------------------------------------------------
// Output projection: attn16[8192,512] @ Wo[512,512]^T + bo -> d_out fp32
// 64x128 tiles -> grid (128,4) = 512 blocks = 2 blocks/CU.
// ---------------------------------------------------------------------------
__global__ __launch_bounds__(256, 4) void gemm_out(
    const _Float16* __restrict__ A, const _Float16* __restrict__ W,
    const float* __restrict__ bo, float* __restrict__ dout)
{
    __shared__ _Float16 As[64 * 32];
    __shared__ _Float16 Bs[128 * 32];
    const int t = threadIdx.x;
    const int bm = blockIdx.x, bn = blockIdx.y;
    const int wave = t >> 6, lane = t & 63;
    const int wm = (wave >> 1) * 32, wn = (wave & 1) * 64;
    const int quad = lane >> 4, l16 = lane & 15;

    f32x4 acc[2][4];
#pragma unroll
    for (int a = 0; a < 2; a++)
#pragma unroll
        for (int b2 = 0; b2 < 4; b2++) acc[a][b2] = (f32x4){0.f, 0.f, 0.f, 0.f};

    const _Float16* Ab = A + (size_t)bm * 64 * 512;
    const _Float16* Bb = W + (size_t)bn * 128 * 512;
    const int srow = t >> 2, scol = (t & 3) * 8;

    for (int k0 = 0; k0 < 512; k0 += 32) {
        __syncthreads();
        lds_load16(Ab + (size_t)srow * 512 + k0 + scol, As + t * 8);
        lds_load16(Bb + (size_t)srow * 512 + k0 + scol, Bs + t * 8);
        lds_load16(Bb + (size_t)(srow + 64) * 512 + k0 + scol, Bs + 2048 + t * 8);
        __syncthreads();
        half8 af[2], bf[4];
#pragma unroll
        for (int mi = 0; mi < 2; mi++)
            af[mi] = *(const half8*)&As[(wm + mi * 16 + l16) * 32 + quad * 8];
#pragma unroll
        for (int ni = 0; ni < 4; ni++)
            bf[ni] = *(const half8*)&Bs[(wn + ni * 16 + l16) * 32 + quad * 8];
#pragma unroll
        for (int mi = 0; mi < 2; mi++)
#pragma unroll
            for (int ni = 0; ni < 4; ni++)
                acc[mi][ni] = __builtin_amdgcn_mfma_f32_16x16x32_f16(
                    af[mi], bf[ni], acc[mi][ni], 0, 0, 0);
    }
#pragma unroll
    for (int mi = 0; mi < 2; mi++) {
#pragma unroll
        for (int r = 0; r < 4; r++) {
            const int m = bm * 64 + wm + mi * 16 + quad * 4 + r;
#pragma unroll
            for (int ni = 0; ni < 4; ni++) {
                const int n = bn * 128 + wn + ni * 16 + l16;
                dout[(size_t)m * 512 + n] = acc[mi][ni][r] + bo[n];
            }
        }
    }
}

// ---------------------------------------------------------------------------
extern "C" void kernel_launch(void* const* d_in, const int* in_sizes, int n_in,
                              void* d_out, int out_size, void* d_ws, size_t ws_size,
                              hipStream_t stream)
{
    (void)in_sizes; (void)n_in; (void)out_size; (void)ws_size;
    const float* nodes    = (const float*)d_in[0];
    const float* edges    = (const float*)d_in[1];
    const float* Wq       = (const float*)d_in[2];
    const float* bq       = (const float*)d_in[3];
    const float* Wk       = (const float*)d_in[4];
    const float* bk       = (const float*)d_in[5];
    const float* Wv       = (const float*)d_in[6];
    const float* bv       = (const float*)d_in[7];
    const float* rel_bias = (const float*)d_in[8];
    const float* Wo       = (const float*)d_in[9];
    const float* bo       = (const float*)d_in[10];
    float* out = (float*)d_out;

    char* ws = (char*)d_ws;
    _Float16* x16    = (_Float16*)(ws);              //  8,388,608 B
    _Float16* wcat   = (_Float16*)(ws +  8388608);   //  1,572,864 B
    _Float16* wo16   = (_Float16*)(ws +  9961472);   //    524,288 B
    _Float16* q16    = (_Float16*)(ws + 10485760);   //  8,388,608 B
    _Float16* k16    = (_Float16*)(ws + 18874368);   //  8,388,608 B
    _Float16* v16    = (_Float16*)(ws + 27262976);   //  8,388,608 B
    _Float16* attn16 = (_Float16*)(ws + 35651584);   //  8,388,608 B

    hipLaunchKernelGGL(prep_convert, dim3(4096), dim3(256), 0, stream,
                       nodes, Wq, Wk, Wv, Wo, x16, wcat, wo16);
    hipLaunchKernelGGL(gemm_qkv, dim3(64, 12), dim3(256), 0, stream,
                       x16, wcat, bq, bk, bv, q16, k16, v16);
    hipLaunchKernelGGL(attn_fused, dim3(64, 4), dim3(512), 0, stream,
                       q16, k16, v16, edges, rel_bias, attn16);
    hipLaunchKernelGGL(gemm_out, dim3(128, 4), dim3(256), 0, stream,
                       attn16, wo16, bo, out);
}